// Round 1
// baseline (1316.365 us; speedup 1.0000x reference)
//
#include <hip/hip_runtime.h>
#include <math.h>

// ---------------- kernels ----------------

__global__ void k_deg(const int* __restrict__ dst, float* __restrict__ deg, int E) {
    int e = blockIdx.x * blockDim.x + threadIdx.x;
    if (e < E) atomicAdd(&deg[dst[e]], 1.0f);
}

__global__ void k_dinv(float* __restrict__ deg, int n) {
    int i = blockIdx.x * blockDim.x + threadIdx.x;
    if (i < n) deg[i] = rsqrtf(deg[i] + 1.0f);   // +1 self loop; always > 0
}

// h1[i, 0..31] = x[i, :] @ W1   (thread per node; W1 reads are wave-uniform -> s_load)
__global__ void k_gemm1(const float* __restrict__ x, const float* __restrict__ W,
                        float* __restrict__ h, int n) {
    int i = blockIdx.x * blockDim.x + threadIdx.x;
    if (i >= n) return;
    float acc[32];
#pragma unroll
    for (int c = 0; c < 32; ++c) acc[c] = 0.f;
    const float4* xr = (const float4*)(x + (size_t)i * 256);
#pragma unroll 4
    for (int k4 = 0; k4 < 64; ++k4) {
        float4 xv = xr[k4];
        const float* w0 = W + k4 * 128;
#pragma unroll
        for (int c = 0; c < 32; ++c) acc[c] += xv.x * w0[c];
#pragma unroll
        for (int c = 0; c < 32; ++c) acc[c] += xv.y * w0[32 + c];
#pragma unroll
        for (int c = 0; c < 32; ++c) acc[c] += xv.z * w0[64 + c];
#pragma unroll
        for (int c = 0; c < 32; ++c) acc[c] += xv.w * w0[96 + c];
    }
    float4* out = (float4*)(h + (size_t)i * 32);
#pragma unroll
    for (int q = 0; q < 8; ++q)
        out[q] = make_float4(acc[q*4], acc[q*4+1], acc[q*4+2], acc[q*4+3]);
}

// agg1 = h1 * dinv^2 (self loop) + b1   (full overwrite -> no memset needed)
__global__ void k_init1(const float* __restrict__ h, const float* __restrict__ dinv,
                        const float* __restrict__ b, float* __restrict__ agg, int n) {
    int t = blockIdx.x * blockDim.x + threadIdx.x;
    if (t >= n * 32) return;
    int i = t >> 5, c = t & 31;
    float di = dinv[i];
    agg[t] = h[t] * di * di + b[c];
}

// scatter layer 1: 32 lanes per edge (2 edges/wave), contiguous 128B gather + atomic
__global__ void k_scat1(const int* __restrict__ src, const int* __restrict__ dst,
                        const float* __restrict__ h, const float* __restrict__ dinv,
                        float* __restrict__ agg, unsigned total) {
    unsigned t = blockIdx.x * blockDim.x + threadIdx.x;
    if (t >= total) return;
    unsigned e = t >> 5, c = t & 31;
    int s = src[e], d = dst[e];
    float norm = dinv[s] * dinv[d];
    atomicAdd(&agg[(size_t)d * 32 + c], h[(size_t)s * 32 + c] * norm);
}

// in-place ELU + per-channel sum/sumsq (grid-stride; stride multiple of 32 keeps
// channel fixed per thread; block-level LDS reduce then 64 atomics/block)
__global__ void k_elu_stats(float* __restrict__ y, float* __restrict__ stats, int total) {
    int stride = gridDim.x * blockDim.x;
    float s0 = 0.f, s1 = 0.f;
    for (int t = blockIdx.x * blockDim.x + threadIdx.x; t < total; t += stride) {
        float v = y[t];
        v = v > 0.f ? v : expm1f(v);
        y[t] = v;
        s0 += v; s1 += v * v;
    }
    __shared__ float ls[256], lq[256];
    ls[threadIdx.x] = s0; lq[threadIdx.x] = s1;
    __syncthreads();
    if (threadIdx.x < 32) {
        float a = 0.f, bq = 0.f;
#pragma unroll
        for (int r = 0; r < 8; ++r) { a += ls[r*32 + threadIdx.x]; bq += lq[r*32 + threadIdx.x]; }
        atomicAdd(&stats[threadIdx.x], a);
        atomicAdd(&stats[32 + threadIdx.x], bq);
    }
}

// BN(normalize, biased var) + ReLU + h2 = hbn @ W2  (thread per node; W2 uniform)
__global__ void k_bn_gemm2(const float* __restrict__ y, const float* __restrict__ stats,
                           const float* __restrict__ W2, float* __restrict__ h2, int n) {
    int i = blockIdx.x * blockDim.x + threadIdx.x;
    if (i >= n) return;
    float invn = 1.0f / (float)n;
    const float* yr = y + (size_t)i * 32;
    float hb[32];
#pragma unroll
    for (int c = 0; c < 32; ++c) {
        float mean = stats[c] * invn;
        float var  = stats[32 + c] * invn - mean * mean;
        float sc   = rsqrtf(var + 1e-5f);
        float v = (yr[c] - mean) * sc;
        hb[c] = v > 0.f ? v : 0.f;
    }
    float o[40];
#pragma unroll
    for (int j = 0; j < 40; ++j) o[j] = 0.f;
#pragma unroll
    for (int c = 0; c < 32; ++c) {
        float v = hb[c];
        const float* wr = W2 + c * 40;
#pragma unroll
        for (int j = 0; j < 40; ++j) o[j] += v * wr[j];
    }
    float* out = h2 + (size_t)i * 40;
#pragma unroll
    for (int j = 0; j < 40; ++j) out[j] = o[j];
}

// out = h2 * dinv^2 + b2  (layer-2 self loop + bias; full overwrite of d_out)
__global__ void k_init2(const float* __restrict__ h2, const float* __restrict__ dinv,
                        const float* __restrict__ b, float* __restrict__ out, int n) {
    int t = blockIdx.x * blockDim.x + threadIdx.x;
    if (t >= n * 40) return;
    int i = t / 40, j = t - i * 40;
    float di = dinv[i];
    out[t] = h2[t] * di * di + b[j];
}

// scatter layer 2: 40 lanes per edge (flat index, magic-div by 40)
__global__ void k_scat2(const int* __restrict__ src, const int* __restrict__ dst,
                        const float* __restrict__ h2, const float* __restrict__ dinv,
                        float* __restrict__ out, unsigned total) {
    unsigned t = blockIdx.x * blockDim.x + threadIdx.x;
    if (t >= total) return;
    unsigned e = t / 40u, j = t - e * 40u;
    int s = src[e], d = dst[e];
    float norm = dinv[s] * dinv[d];
    atomicAdd(&out[(size_t)d * 40 + j], h2[(size_t)s * 40 + j] * norm);
}

// in-place log_softmax over 40 classes, thread per node
__global__ void k_lsm(float* __restrict__ out, int n) {
    int i = blockIdx.x * blockDim.x + threadIdx.x;
    if (i >= n) return;
    float* r = out + (size_t)i * 40;
    float v[40];
    float mx = -INFINITY;
#pragma unroll
    for (int j = 0; j < 40; ++j) { v[j] = r[j]; mx = fmaxf(mx, v[j]); }
    float s = 0.f;
#pragma unroll
    for (int j = 0; j < 40; ++j) s += expf(v[j] - mx);
    float lse = mx + logf(s);
#pragma unroll
    for (int j = 0; j < 40; ++j) r[j] = v[j] - lse;
}

// ---------------- launcher ----------------

extern "C" void kernel_launch(void* const* d_in, const int* in_sizes, int n_in,
                              void* d_out, int out_size, void* d_ws, size_t ws_size,
                              hipStream_t stream) {
    const float* x  = (const float*)d_in[0];
    const int*   ei = (const int*)d_in[1];
    const float* W1 = (const float*)d_in[2];
    const float* b1 = (const float*)d_in[3];
    const float* W2 = (const float*)d_in[4];
    const float* b2 = (const float*)d_in[5];

    int n = in_sizes[0] / 256;     // 100000
    int E = in_sizes[1] / 2;       // 3200000
    const int* src = ei;
    const int* dst = ei + E;

    float* ws    = (float*)d_ws;
    float* dinv  = ws;                          // N
    float* h1    = dinv + n;                    // 32N
    float* agg1  = h1   + (size_t)n * 32;       // 32N
    float* h2    = agg1 + (size_t)n * 32;       // 40N
    float* stats = h2   + (size_t)n * 40;       // 64
    float* out   = (float*)d_out;

    const int B = 256;
    hipMemsetAsync(dinv, 0, (size_t)n * sizeof(float), stream);
    hipMemsetAsync(stats, 0, 64 * sizeof(float), stream);

    k_deg <<<(E + B - 1) / B, B, 0, stream>>>(dst, dinv, E);
    k_dinv<<<(n + B - 1) / B, B, 0, stream>>>(dinv, n);
    k_gemm1<<<(n + B - 1) / B, B, 0, stream>>>(x, W1, h1, n);
    k_init1<<<((n * 32) + B - 1) / B, B, 0, stream>>>(h1, dinv, b1, agg1, n);
    unsigned tot1 = (unsigned)E * 32u;
    k_scat1<<<(tot1 + B - 1) / B, B, 0, stream>>>(src, dst, h1, dinv, agg1, tot1);
    k_elu_stats<<<1024, B, 0, stream>>>(agg1, stats, n * 32);
    k_bn_gemm2<<<(n + B - 1) / B, B, 0, stream>>>(agg1, stats, W2, h2, n);
    k_init2<<<((n * 40) + B - 1) / B, B, 0, stream>>>(h2, dinv, b2, out, n);
    unsigned tot2 = (unsigned)E * 40u;
    k_scat2<<<(tot2 + B - 1) / B, B, 0, stream>>>(src, dst, h2, dinv, out, tot2);
    k_lsm <<<(n + B - 1) / B, B, 0, stream>>>(out, n);
}

// Round 2
// 900.989 us; speedup vs baseline: 1.4610x; 1.4610x over previous
//
#include <hip/hip_runtime.h>
#include <math.h>

// ---------------- CSR build ----------------

__global__ void k_count(const int* __restrict__ dst, int* __restrict__ deg, int E) {
    int e = blockIdx.x * blockDim.x + threadIdx.x;
    if (e < E) atomicAdd(&deg[dst[e]], 1);
}

// per-256-chunk exclusive scan + block totals
__global__ void k_scan_block(const int* __restrict__ deg, int* __restrict__ rowptr,
                             int* __restrict__ bsum, int n) {
    __shared__ int ls[256];
    int gid = blockIdx.x * 256 + threadIdx.x;
    int v = (gid < n) ? deg[gid] : 0;
    ls[threadIdx.x] = v;
    __syncthreads();
    for (int off = 1; off < 256; off <<= 1) {
        int t = (threadIdx.x >= off) ? ls[threadIdx.x - off] : 0;
        __syncthreads();
        ls[threadIdx.x] += t;
        __syncthreads();
    }
    if (gid < n) rowptr[gid] = ls[threadIdx.x] - v;   // exclusive within chunk
    if (threadIdx.x == 255) bsum[blockIdx.x] = ls[255];
}

// exclusive scan of block sums (nb <= 512), single block
__global__ void k_scan_bsum(int* __restrict__ bsum, int nb) {
    __shared__ int ls[512];
    int v = (threadIdx.x < nb) ? bsum[threadIdx.x] : 0;
    ls[threadIdx.x] = v;
    __syncthreads();
    for (int off = 1; off < 512; off <<= 1) {
        int t = (threadIdx.x >= off) ? ls[threadIdx.x - off] : 0;
        __syncthreads();
        ls[threadIdx.x] += t;
        __syncthreads();
    }
    if (threadIdx.x < nb) bsum[threadIdx.x] = ls[threadIdx.x] - v;  // exclusive
}

// finalize rowptr, init cursor, compute dinv
__global__ void k_scan_add(int* __restrict__ rowptr, int* __restrict__ cursor,
                           const int* __restrict__ bsum, const int* __restrict__ deg,
                           float* __restrict__ dinv, int n, int E) {
    int gid = blockIdx.x * 256 + threadIdx.x;
    if (gid < n) {
        int r = rowptr[gid] + bsum[blockIdx.x];
        rowptr[gid] = r;
        cursor[gid] = r;
        dinv[gid] = rsqrtf((float)deg[gid] + 1.0f);   // +1 self loop
    }
    if (gid == 0) rowptr[n] = E;
}

__global__ void k_fill(const int* __restrict__ src, const int* __restrict__ dst,
                       int* __restrict__ cursor, int* __restrict__ adj, int E) {
    int e = blockIdx.x * blockDim.x + threadIdx.x;
    if (e < E) {
        int pos = atomicAdd(&cursor[dst[e]], 1);
        adj[pos] = src[e];
    }
}

// ---------------- compute ----------------

// hs[i, 0..31] = (x[i,:] @ W1) * dinv[i]
__global__ void k_gemm1(const float* __restrict__ x, const float* __restrict__ W,
                        const float* __restrict__ dinv, float* __restrict__ h, int n) {
    int i = blockIdx.x * blockDim.x + threadIdx.x;
    if (i >= n) return;
    float acc[32];
#pragma unroll
    for (int c = 0; c < 32; ++c) acc[c] = 0.f;
    const float4* xr = (const float4*)(x + (size_t)i * 256);
#pragma unroll 4
    for (int k4 = 0; k4 < 64; ++k4) {
        float4 xv = xr[k4];
        const float* w0 = W + k4 * 128;
#pragma unroll
        for (int c = 0; c < 32; ++c) acc[c] += xv.x * w0[c];
#pragma unroll
        for (int c = 0; c < 32; ++c) acc[c] += xv.y * w0[32 + c];
#pragma unroll
        for (int c = 0; c < 32; ++c) acc[c] += xv.z * w0[64 + c];
#pragma unroll
        for (int c = 0; c < 32; ++c) acc[c] += xv.w * w0[96 + c];
    }
    float di = dinv[i];
    float4* out = (float4*)(h + (size_t)i * 32);
#pragma unroll
    for (int q = 0; q < 8; ++q)
        out[q] = make_float4(acc[q*4]*di, acc[q*4+1]*di, acc[q*4+2]*di, acc[q*4+3]*di);
}

// gather-aggregate: out[d,c] = dinv[d]*(sum_{s in in(d)} hs[s,c] + hs[d,c]) (+b[c]) (ELU?)
// 32 lanes per node, 8 nodes per 256-block
template <bool ELU_BIAS>
__global__ void k_agg(const float* __restrict__ hs, const int* __restrict__ rowptr,
                      const int* __restrict__ adj, const float* __restrict__ dinv,
                      const float* __restrict__ b, float* __restrict__ out, int n) {
    int d = blockIdx.x * 8 + (threadIdx.x >> 5);
    int c = threadIdx.x & 31;
    if (d >= n) return;
    float acc = hs[(size_t)d * 32 + c];          // self loop term (already *dinv[d] via hs? no: hs=h*dinv[src]; self uses dinv[d] twice -> hs[d]*dinv[d] handled by outer dinv[d])
    int k = rowptr[d], end = rowptr[d + 1];
    for (; k + 2 <= end; k += 2) {
        int s0 = adj[k], s1 = adj[k + 1];
        float v0 = hs[(size_t)s0 * 32 + c];
        float v1 = hs[(size_t)s1 * 32 + c];
        acc += v0 + v1;
    }
    if (k < end) acc += hs[(size_t)adj[k] * 32 + c];
    float v = dinv[d] * acc;
    if (ELU_BIAS) {
        v += b[c];
        v = v > 0.f ? v : expm1f(v);             // ELU fused
    }
    out[(size_t)d * 32 + c] = v;
}

// per-channel sum/sumsq of y (read-only; ELU already applied)
__global__ void k_stats(const float* __restrict__ y, float* __restrict__ stats, int total) {
    int stride = gridDim.x * blockDim.x;          // multiple of 32 -> channel fixed
    float s0 = 0.f, s1 = 0.f;
    for (int t = blockIdx.x * blockDim.x + threadIdx.x; t < total; t += stride) {
        float v = y[t];
        s0 += v; s1 += v * v;
    }
    __shared__ float ls[256], lq[256];
    ls[threadIdx.x] = s0; lq[threadIdx.x] = s1;
    __syncthreads();
    if (threadIdx.x < 32) {
        float a = 0.f, bq = 0.f;
#pragma unroll
        for (int r = 0; r < 8; ++r) { a += ls[r*32 + threadIdx.x]; bq += lq[r*32 + threadIdx.x]; }
        atomicAdd(&stats[threadIdx.x], a);
        atomicAdd(&stats[32 + threadIdx.x], bq);
    }
}

// h2s = relu(BN(y)) * dinv[i]
__global__ void k_bn2(const float* __restrict__ y, const float* __restrict__ stats,
                      const float* __restrict__ dinv, float* __restrict__ h2s, int n) {
    int t = blockIdx.x * blockDim.x + threadIdx.x;
    if (t >= n * 32) return;
    int i = t >> 5, c = t & 31;
    float invn = 1.0f / (float)n;
    float mean = stats[c] * invn;
    float var  = stats[32 + c] * invn - mean * mean;
    float v = (y[t] - mean) * rsqrtf(var + 1e-5f);
    v = v > 0.f ? v : 0.f;
    h2s[t] = v * dinv[i];
}

// out[i,:] = log_softmax( t[i,:] @ W2 + b2 )
__global__ void k_out(const float* __restrict__ tin, const float* __restrict__ W2,
                      const float* __restrict__ b2, float* __restrict__ out, int n) {
    int i = blockIdx.x * blockDim.x + threadIdx.x;
    if (i >= n) return;
    const float* tr = tin + (size_t)i * 32;
    float o[40];
#pragma unroll
    for (int j = 0; j < 40; ++j) o[j] = b2[j];
#pragma unroll
    for (int c = 0; c < 32; ++c) {
        float v = tr[c];
        const float* wr = W2 + c * 40;
#pragma unroll
        for (int j = 0; j < 40; ++j) o[j] += v * wr[j];
    }
    float mx = -INFINITY;
#pragma unroll
    for (int j = 0; j < 40; ++j) mx = fmaxf(mx, o[j]);
    float s = 0.f;
#pragma unroll
    for (int j = 0; j < 40; ++j) s += expf(o[j] - mx);
    float lse = mx + logf(s);
    float* r = out + (size_t)i * 40;
#pragma unroll
    for (int j = 0; j < 40; ++j) r[j] = o[j] - lse;
}

// ---------------- launcher ----------------

static inline size_t rnd4(size_t x) { return (x + 3) & ~(size_t)3; }

extern "C" void kernel_launch(void* const* d_in, const int* in_sizes, int n_in,
                              void* d_out, int out_size, void* d_ws, size_t ws_size,
                              hipStream_t stream) {
    const float* x  = (const float*)d_in[0];
    const int*   ei = (const int*)d_in[1];
    const float* W1 = (const float*)d_in[2];
    const float* b1 = (const float*)d_in[3];
    const float* W2 = (const float*)d_in[4];
    const float* b2 = (const float*)d_in[5];

    int n = in_sizes[0] / 256;     // 100000
    int E = in_sizes[1] / 2;       // 3200000
    const int* src = ei;
    const int* dst = ei + E;

    // workspace layout (elements, 4B each), each region rounded to x4 for alignment
    char* base = (char*)d_ws;
    size_t off = 0;
    int*   deg    = (int*)(base + off); off += rnd4((size_t)n) * 4;
    int*   rowptr = (int*)(base + off); off += rnd4((size_t)n + 1) * 4;
    int*   cursor = (int*)(base + off); off += rnd4((size_t)n) * 4;
    int*   bsum   = (int*)(base + off); off += 512 * 4;
    int*   adj    = (int*)(base + off); off += rnd4((size_t)E) * 4;
    float* dinv   = (float*)(base + off); off += rnd4((size_t)n) * 4;
    float* bufA   = (float*)(base + off); off += (size_t)n * 32 * 4;
    float* bufB   = (float*)(base + off); off += (size_t)n * 32 * 4;
    float* stats  = (float*)(base + off); off += 64 * 4;
    float* out    = (float*)d_out;

    const int B = 256;
    int nbE = (E + B - 1) / B;
    int nbN = (n + B - 1) / B;

    hipMemsetAsync(deg, 0, (size_t)n * sizeof(int), stream);
    hipMemsetAsync(stats, 0, 64 * sizeof(float), stream);

    // CSR build
    k_count     <<<nbE, B, 0, stream>>>(dst, deg, E);
    k_scan_block<<<nbN, B, 0, stream>>>(deg, rowptr, bsum, n);
    k_scan_bsum <<<1, 512, 0, stream>>>(bsum, nbN);
    k_scan_add  <<<nbN, B, 0, stream>>>(rowptr, cursor, bsum, deg, dinv, n, E);
    k_fill      <<<nbE, B, 0, stream>>>(src, dst, cursor, adj, E);

    // layer 1: hs = (x@W1)*dinv  -> aggregate (+b1, ELU)
    k_gemm1<<<nbN, B, 0, stream>>>(x, W1, dinv, bufA, n);
    k_agg<true><<<(n + 7) / 8, B, 0, stream>>>(bufA, rowptr, adj, dinv, b1, bufB, n);

    // BN stats + normalize + relu + pre-scale by dinv
    k_stats<<<1024, B, 0, stream>>>(bufB, stats, n * 32);
    k_bn2  <<<(n * 32 + B - 1) / B, B, 0, stream>>>(bufB, stats, dinv, bufA, n);

    // layer 2: aggregate 32-dim (linearity: A@(h@W2) == (A@h)@W2), then W2+b2+lsm
    k_agg<false><<<(n + 7) / 8, B, 0, stream>>>(bufA, rowptr, adj, dinv, (const float*)nullptr, bufB, n);
    k_out<<<nbN, B, 0, stream>>>(bufB, W2, b2, out, n);
}

// Round 3
// 698.125 us; speedup vs baseline: 1.8856x; 1.2906x over previous
//
#include <hip/hip_runtime.h>
#include <math.h>

// ---------------- CSR build ----------------

// count in-degree (padded: one counter per 64B line) and record each edge's
// local slot within its destination's list (the atomic's return value).
__global__ void k_count(const int* __restrict__ dst, int* __restrict__ degp,
                        int* __restrict__ off, int E) {
    int e = blockIdx.x * blockDim.x + threadIdx.x;
    if (e < E) off[e] = atomicAdd(&degp[(size_t)dst[e] * 16], 1);
}

// per-256-chunk exclusive scan + block totals (reads padded deg)
__global__ void k_scan_block(const int* __restrict__ degp, int* __restrict__ rowptr,
                             int* __restrict__ bsum, int n) {
    __shared__ int ls[256];
    int gid = blockIdx.x * 256 + threadIdx.x;
    int v = (gid < n) ? degp[(size_t)gid * 16] : 0;
    ls[threadIdx.x] = v;
    __syncthreads();
    for (int off = 1; off < 256; off <<= 1) {
        int t = (threadIdx.x >= off) ? ls[threadIdx.x - off] : 0;
        __syncthreads();
        ls[threadIdx.x] += t;
        __syncthreads();
    }
    if (gid < n) rowptr[gid] = ls[threadIdx.x] - v;   // exclusive within chunk
    if (threadIdx.x == 255) bsum[blockIdx.x] = ls[255];
}

// exclusive scan of block sums (nb <= 512), single block
__global__ void k_scan_bsum(int* __restrict__ bsum, int nb) {
    __shared__ int ls[512];
    int v = (threadIdx.x < nb) ? bsum[threadIdx.x] : 0;
    ls[threadIdx.x] = v;
    __syncthreads();
    for (int off = 1; off < 512; off <<= 1) {
        int t = (threadIdx.x >= off) ? ls[threadIdx.x - off] : 0;
        __syncthreads();
        ls[threadIdx.x] += t;
        __syncthreads();
    }
    if (threadIdx.x < nb) bsum[threadIdx.x] = ls[threadIdx.x] - v;  // exclusive
}

// finalize rowptr, compute dinv
__global__ void k_scan_add(int* __restrict__ rowptr, const int* __restrict__ bsum,
                           const int* __restrict__ degp, float* __restrict__ dinv,
                           int n, int E) {
    int gid = blockIdx.x * 256 + threadIdx.x;
    if (gid < n) {
        rowptr[gid] += bsum[blockIdx.x];
        dinv[gid] = rsqrtf((float)degp[(size_t)gid * 16] + 1.0f);   // +1 self loop
    }
    if (gid == 0) rowptr[n] = E;
}

// atomic-free fill: slot was precomputed in k_count
__global__ void k_fill(const int* __restrict__ src, const int* __restrict__ dst,
                       const int* __restrict__ off, const int* __restrict__ rowptr,
                       int* __restrict__ adj, int E) {
    int e = blockIdx.x * blockDim.x + threadIdx.x;
    if (e < E) adj[rowptr[dst[e]] + off[e]] = src[e];
}

// ---------------- compute ----------------

// hs[i, 0..31] = (x[i,:] @ W1) * dinv[i]
__global__ void k_gemm1(const float* __restrict__ x, const float* __restrict__ W,
                        const float* __restrict__ dinv, float* __restrict__ h, int n) {
    int i = blockIdx.x * blockDim.x + threadIdx.x;
    if (i >= n) return;
    float acc[32];
#pragma unroll
    for (int c = 0; c < 32; ++c) acc[c] = 0.f;
    const float4* xr = (const float4*)(x + (size_t)i * 256);
#pragma unroll 4
    for (int k4 = 0; k4 < 64; ++k4) {
        float4 xv = xr[k4];
        const float* w0 = W + k4 * 128;
#pragma unroll
        for (int c = 0; c < 32; ++c) acc[c] += xv.x * w0[c];
#pragma unroll
        for (int c = 0; c < 32; ++c) acc[c] += xv.y * w0[32 + c];
#pragma unroll
        for (int c = 0; c < 32; ++c) acc[c] += xv.z * w0[64 + c];
#pragma unroll
        for (int c = 0; c < 32; ++c) acc[c] += xv.w * w0[96 + c];
    }
    float di = dinv[i];
    float4* out = (float4*)(h + (size_t)i * 32);
#pragma unroll
    for (int q = 0; q < 8; ++q)
        out[q] = make_float4(acc[q*4]*di, acc[q*4+1]*di, acc[q*4+2]*di, acc[q*4+3]*di);
}

// gather-aggregate: out[d,c] = dinv[d]*(sum_{s in in(d)} hs[s,c] + hs[d,c]) (+b[c], ELU)
// 32 lanes per node, 8 nodes per 256-block, 4-wide unrolled gather for MLP
template <bool ELU_BIAS>
__global__ void k_agg(const float* __restrict__ hs, const int* __restrict__ rowptr,
                      const int* __restrict__ adj, const float* __restrict__ dinv,
                      const float* __restrict__ b, float* __restrict__ out, int n) {
    int d = blockIdx.x * 8 + (threadIdx.x >> 5);
    int c = threadIdx.x & 31;
    if (d >= n) return;
    float a0 = hs[(size_t)d * 32 + c];          // self-loop term
    float a1 = 0.f, a2 = 0.f, a3 = 0.f;
    int k = rowptr[d], end = rowptr[d + 1];
    for (; k + 4 <= end; k += 4) {
        int s0 = adj[k], s1 = adj[k + 1], s2 = adj[k + 2], s3 = adj[k + 3];
        a0 += hs[(size_t)s0 * 32 + c];
        a1 += hs[(size_t)s1 * 32 + c];
        a2 += hs[(size_t)s2 * 32 + c];
        a3 += hs[(size_t)s3 * 32 + c];
    }
    for (; k < end; ++k) a0 += hs[(size_t)adj[k] * 32 + c];
    float v = dinv[d] * ((a0 + a1) + (a2 + a3));
    if (ELU_BIAS) {
        v += b[c];
        v = v > 0.f ? v : expm1f(v);             // ELU fused
    }
    out[(size_t)d * 32 + c] = v;
}

// per-channel sum/sumsq of y
__global__ void k_stats(const float* __restrict__ y, float* __restrict__ stats, int total) {
    int stride = gridDim.x * blockDim.x;          // multiple of 32 -> channel fixed
    float s0 = 0.f, s1 = 0.f;
    for (int t = blockIdx.x * blockDim.x + threadIdx.x; t < total; t += stride) {
        float v = y[t];
        s0 += v; s1 += v * v;
    }
    __shared__ float ls[256], lq[256];
    ls[threadIdx.x] = s0; lq[threadIdx.x] = s1;
    __syncthreads();
    if (threadIdx.x < 32) {
        float a = 0.f, bq = 0.f;
#pragma unroll
        for (int r = 0; r < 8; ++r) { a += ls[r*32 + threadIdx.x]; bq += lq[r*32 + threadIdx.x]; }
        atomicAdd(&stats[threadIdx.x], a);
        atomicAdd(&stats[32 + threadIdx.x], bq);
    }
}

// h2s = relu(BN(y)) * dinv[i]
__global__ void k_bn2(const float* __restrict__ y, const float* __restrict__ stats,
                      const float* __restrict__ dinv, float* __restrict__ h2s, int n) {
    int t = blockIdx.x * blockDim.x + threadIdx.x;
    if (t >= n * 32) return;
    int i = t >> 5, c = t & 31;
    float invn = 1.0f / (float)n;
    float mean = stats[c] * invn;
    float var  = stats[32 + c] * invn - mean * mean;
    float v = (y[t] - mean) * rsqrtf(var + 1e-5f);
    v = v > 0.f ? v : 0.f;
    h2s[t] = v * dinv[i];
}

// out[i,:] = log_softmax( t[i,:] @ W2 + b2 )
__global__ void k_out(const float* __restrict__ tin, const float* __restrict__ W2,
                      const float* __restrict__ b2, float* __restrict__ out, int n) {
    int i = blockIdx.x * blockDim.x + threadIdx.x;
    if (i >= n) return;
    const float* tr = tin + (size_t)i * 32;
    float o[40];
#pragma unroll
    for (int j = 0; j < 40; ++j) o[j] = b2[j];
#pragma unroll
    for (int c = 0; c < 32; ++c) {
        float v = tr[c];
        const float* wr = W2 + c * 40;
#pragma unroll
        for (int j = 0; j < 40; ++j) o[j] += v * wr[j];
    }
    float mx = -INFINITY;
#pragma unroll
    for (int j = 0; j < 40; ++j) mx = fmaxf(mx, o[j]);
    float s = 0.f;
#pragma unroll
    for (int j = 0; j < 40; ++j) s += expf(o[j] - mx);
    float lse = mx + logf(s);
    float* r = out + (size_t)i * 40;
#pragma unroll
    for (int j = 0; j < 40; ++j) r[j] = o[j] - lse;
}

// ---------------- launcher ----------------

static inline size_t rnd4(size_t x) { return (x + 3) & ~(size_t)3; }

extern "C" void kernel_launch(void* const* d_in, const int* in_sizes, int n_in,
                              void* d_out, int out_size, void* d_ws, size_t ws_size,
                              hipStream_t stream) {
    const float* x  = (const float*)d_in[0];
    const int*   ei = (const int*)d_in[1];
    const float* W1 = (const float*)d_in[2];
    const float* b1 = (const float*)d_in[3];
    const float* W2 = (const float*)d_in[4];
    const float* b2 = (const float*)d_in[5];

    int n = in_sizes[0] / 256;     // 100000
    int E = in_sizes[1] / 2;       // 3200000
    const int* src = ei;
    const int* dst = ei + E;

    // workspace layout; off aliases bufA, padded deg aliases bufB
    char* base = (char*)d_ws;
    size_t offb = 0;
    int*   rowptr = (int*)(base + offb); offb += rnd4((size_t)n + 1) * 4;
    int*   bsum   = (int*)(base + offb); offb += 512 * 4;
    int*   adj    = (int*)(base + offb); offb += rnd4((size_t)E) * 4;
    float* dinv   = (float*)(base + offb); offb += rnd4((size_t)n) * 4;
    float* bufA   = (float*)(base + offb); offb += (size_t)n * 32 * 4;   // also: off[E]
    float* bufB   = (float*)(base + offb); offb += (size_t)n * 32 * 4;   // also: degp[16n]
    float* stats  = (float*)(base + offb); offb += 64 * 4;
    int*   off    = (int*)bufA;            // E ints, dead after k_fill
    int*   degp   = (int*)bufB;            // 16n ints padded, dead after k_scan_add
    float* out    = (float*)d_out;

    const int B = 256;
    int nbE = (E + B - 1) / B;
    int nbN = (n + B - 1) / B;

    hipMemsetAsync(degp, 0, (size_t)n * 16 * sizeof(int), stream);
    hipMemsetAsync(stats, 0, 64 * sizeof(float), stream);

    // CSR build (single atomic pass; fill is atomic-free)
    k_count     <<<nbE, B, 0, stream>>>(dst, degp, off, E);
    k_scan_block<<<nbN, B, 0, stream>>>(degp, rowptr, bsum, n);
    k_scan_bsum <<<1, 512, 0, stream>>>(bsum, nbN);
    k_scan_add  <<<nbN, B, 0, stream>>>(rowptr, bsum, degp, dinv, n, E);
    k_fill      <<<nbE, B, 0, stream>>>(src, dst, off, rowptr, adj, E);

    // layer 1: hs = (x@W1)*dinv -> aggregate (+b1, ELU)
    k_gemm1<<<nbN, B, 0, stream>>>(x, W1, dinv, bufA, n);
    k_agg<true><<<(n + 7) / 8, B, 0, stream>>>(bufA, rowptr, adj, dinv, b1, bufB, n);

    // BN stats + normalize + relu + pre-scale by dinv
    k_stats<<<1024, B, 0, stream>>>(bufB, stats, n * 32);
    k_bn2  <<<(n * 32 + B - 1) / B, B, 0, stream>>>(bufB, stats, dinv, bufA, n);

    // layer 2: aggregate 32-dim (linearity: A@(h@W2) == (A@h)@W2), then W2+b2+lsm
    k_agg<false><<<(n + 7) / 8, B, 0, stream>>>(bufA, rowptr, adj, dinv, (const float*)nullptr, bufB, n);
    k_out<<<nbN, B, 0, stream>>>(bufB, W2, b2, out, n);
}